// Round 2
// baseline (704.417 us; speedup 1.0000x reference)
//
#include <hip/hip_runtime.h>
#include <float.h>
#include <stdint.h>

#define BB 4
#define NN 20000
#define MM 1024
#define CAP 256
#define KSEL 50

// order-preserving float -> uint32 map (total order incl. negatives)
__device__ __forceinline__ unsigned int fkey(float d) {
    unsigned int u = __float_as_uint(d);
    return (u & 0x80000000u) ? ~u : (u | 0x80000000u);
}

// pack keypoints as float4 {x,y,z,|k|^2}
__global__ __launch_bounds__(256) void k_prep(const float* __restrict__ kp,
                                              float4* __restrict__ kp4) {
    int i = blockIdx.x * 256 + threadIdx.x;   // over BB*MM
    if (i >= BB * MM) return;
    float x = kp[i * 3 + 0], y = kp[i * 3 + 1], z = kp[i * 3 + 2];
    kp4[i] = make_float4(x, y, z, x * x + y * y + z * z);
}

// one thread per point: argmin over 1024 keypoints (LDS-staged), transform,
// scatter-accumulate into per-node sums, record membership for rare paths.
__global__ __launch_bounds__(64) void k_assign(
    const float* __restrict__ pts, const float4* __restrict__ kp4,
    const float* __restrict__ pose,
    int* __restrict__ p2n, float* __restrict__ dsq,
    float* __restrict__ ptx, float* __restrict__ pty, float* __restrict__ ptz,
    int* __restrict__ cnt, int* __restrict__ lst,
    float* __restrict__ nodesum)
{
    __shared__ float4 skp[MM];                 // 16 KB
    const int b = blockIdx.y;
    for (int j = threadIdx.x; j < MM; j += 64) skp[j] = kp4[b * MM + j];
    __syncthreads();

    const int n = blockIdx.x * 64 + threadIdx.x;
    if (n >= NN) return;
    const float* p = pts + (b * NN + n) * 3;
    const float px = p[0], py = p[1], pz = p[2];
    const float psq = px * px + py * py + pz * pz;

    float best = FLT_MAX; int bi = 0;
    #pragma unroll 8
    for (int j = 0; j < MM; ++j) {
        float4 q = skp[j];                     // ds_read_b128, broadcast
        float dot = q.x * px + q.y * py + q.z * pz;
        float d = (q.w + psq) - 2.0f * dot;    // reference's formula
        if (d < best) { best = d; bi = j; }    // strict < : first-min (jnp.argmin)
    }

    const float* P = pose + b * 16;
    float tx = P[0] * px + P[1] * py + P[2]  * pz + P[3];
    float ty = P[4] * px + P[5] * py + P[6]  * pz + P[7];
    float tz = P[8] * px + P[9] * py + P[10] * pz + P[11];

    int g = b * NN + n;
    p2n[g] = bi; dsq[g] = best;
    ptx[g] = tx; pty[g] = ty; ptz[g] = tz;

    int node = b * MM + bi;
    atomicAdd(&nodesum[node * 4 + 0], tx);     // ~20 adds/node: low contention
    atomicAdd(&nodesum[node * 4 + 1], ty);
    atomicAdd(&nodesum[node * 4 + 2], tz);
    int s = atomicAdd(&cnt[node], 1);
    if (s < CAP) lst[node * CAP + s] = n;
}

// one THREAD per node; 16 blocks total; 2 atomics per block.
__global__ __launch_bounds__(256) void k_node(
    const int* __restrict__ p2n, const float* __restrict__ dsq,
    const float* __restrict__ ptx, const float* __restrict__ pty, const float* __restrict__ ptz,
    const int* __restrict__ cnt, const int* __restrict__ lst,
    const float* __restrict__ nodesum,
    const float* __restrict__ kpw, const float* __restrict__ ow,
    float* __restrict__ acc)
{
    const int node = blockIdx.x * 256 + threadIdx.x;   // 0..4095
    const int b = node >> 10;
    const int m = node & (MM - 1);
    const int base = b * NN;
    const int c = cnt[node];
    float sx, sy, sz;

    if (c <= KSEL) {
        // all members already summed in nodesum; add (50-c) lowest-index
        // non-member fillers — provably all within n in [0,50).
        sx = nodesum[node * 4 + 0];
        sy = nodesum[node * 4 + 1];
        sz = nodesum[node * 4 + 2];
        int k = KSEL - c;
        #pragma unroll
        for (int j = 0; j < KSEL; ++j) {
            // p2n[base+j], pt*[base+j] are wave-uniform addresses (same b per block)
            bool take = (k > 0) && (p2n[base + j] != m);
            if (take) {
                sx += ptx[base + j]; sy += pty[base + j]; sz += ptz[base + j];
                --k;
            }
        }
    } else if (c <= CAP) {
        // rare: exact 50-smallest by (dist, idx), in-thread extraction
        sx = sy = sz = 0.f;
        unsigned long long last = 0ULL;
        for (int r = 0; r < KSEL; ++r) {
            unsigned long long bestk = ~0ULL;
            for (int s = 0; s < c; ++s) {
                int n = lst[node * CAP + s];
                unsigned long long key =
                    ((unsigned long long)fkey(dsq[base + n]) << 32) | (unsigned int)n;
                if (key > last && key < bestk) bestk = key;
            }
            last = bestk;
            int idx = (int)(unsigned int)(bestk & 0xFFFFFFFFULL);
            sx += ptx[base + idx]; sy += pty[base + idx]; sz += ptz[base + idx];
        }
    } else {
        // pathological overflow: rescan all points
        sx = sy = sz = 0.f;
        unsigned long long last = 0ULL;
        for (int r = 0; r < KSEL; ++r) {
            unsigned long long bestk = ~0ULL;
            for (int n = 0; n < NN; ++n) {
                if (p2n[base + n] == m) {
                    unsigned long long key =
                        ((unsigned long long)fkey(dsq[base + n]) << 32) | (unsigned int)n;
                    if (key > last && key < bestk) bestk = key;
                }
            }
            last = bestk;
            int idx = (int)(unsigned int)(bestk & 0xFFFFFFFFULL);
            sx += ptx[base + idx]; sy += pty[base + idx]; sz += ptz[base + idx];
        }
    }

    const float inv = 1.0f / (float)KSEL;
    float ex = sx * inv - kpw[node * 3 + 0];
    float ey = sy * inv - kpw[node * 3 + 1];
    float ez = sz * inv - kpw[node * 3 + 2];
    float w = ow[node];
    float v = (fabsf(ex) + fabsf(ey) + fabsf(ez)) * w;

    // block reduction: wave shuffle then LDS across 4 waves
    float wv = w;
    #pragma unroll
    for (int off = 32; off; off >>= 1) {
        v  += __shfl_down(v, off);
        wv += __shfl_down(wv, off);
    }
    __shared__ float red[8];
    const int lane = threadIdx.x & 63, wid = threadIdx.x >> 6;
    if (lane == 0) { red[wid * 2] = v; red[wid * 2 + 1] = wv; }
    __syncthreads();
    if (threadIdx.x == 0) {
        atomicAdd(&acc[0], red[0] + red[2] + red[4] + red[6]);
        atomicAdd(&acc[1], red[1] + red[3] + red[5] + red[7]);
    }
}

__global__ void k_final(const float* __restrict__ acc, float* __restrict__ out) {
    out[0] = acc[0] / fmaxf(acc[1], 1e-6f);
}

extern "C" void kernel_launch(void* const* d_in, const int* in_sizes, int n_in,
                              void* d_out, int out_size, void* d_ws, size_t ws_size,
                              hipStream_t stream) {
    const float* pts  = (const float*)d_in[0];  // B,N,3
    const float* kp   = (const float*)d_in[1];  // B,M,3
    const float* kpw  = (const float*)d_in[2];  // B,M,3
    const float* pose = (const float*)d_in[3];  // B,4,4
    const float* ow   = (const float*)d_in[4];  // B,M
    float* out = (float*)d_out;

    char* ws = (char*)d_ws;
    size_t off = 0;
    float* acc     = (float*)(ws + off); off += 16;                        // 2 floats
    int*   cnt     = (int*)(ws + off);   off += (size_t)BB * MM * 4;       // 16 KB
    float* nodesum = (float*)(ws + off); off += (size_t)BB * MM * 16;      // 64 KB
    const size_t zero_bytes = off;                                          // acc+cnt+nodesum
    float4* kp4 = (float4*)(ws + off); off += (size_t)BB * MM * 16;        // 64 KB
    int*   p2n = (int*)(ws + off);   off += (size_t)BB * NN * 4;
    float* dsq = (float*)(ws + off); off += (size_t)BB * NN * 4;
    float* ptx = (float*)(ws + off); off += (size_t)BB * NN * 4;
    float* pty = (float*)(ws + off); off += (size_t)BB * NN * 4;
    float* ptz = (float*)(ws + off); off += (size_t)BB * NN * 4;
    int*   lst = (int*)(ws + off);   off += (size_t)BB * MM * CAP * 4;     // 4 MB

    hipMemsetAsync(d_ws, 0, zero_bytes, stream);

    k_prep<<<(BB * MM + 255) / 256, 256, 0, stream>>>(kp, kp4);
    dim3 g1((NN + 63) / 64, BB);
    k_assign<<<g1, 64, 0, stream>>>(pts, kp4, pose, p2n, dsq, ptx, pty, ptz,
                                    cnt, lst, nodesum);
    k_node<<<BB * MM / 256, 256, 0, stream>>>(p2n, dsq, ptx, pty, ptz, cnt, lst,
                                              nodesum, kpw, ow, acc);
    k_final<<<1, 1, 0, stream>>>(acc, out);
}

// Round 3
// 170.810 us; speedup vs baseline: 4.1240x; 4.1240x over previous
//
#include <hip/hip_runtime.h>
#include <float.h>
#include <stdint.h>

#define BB 4
#define NN 20000
#define MM 1024
#define CAP 256
#define KSEL 50
#define AB 128          // k_assign block threads
#define PPT 2           // points per thread in k_assign
#define NODEBLK 128     // k_node blocks (4 waves each -> 512 waves, 8 nodes/wave)

// order-preserving float -> uint32 map (total order incl. negatives)
__device__ __forceinline__ unsigned int fkey(float d) {
    unsigned int u = __float_as_uint(d);
    return (u & 0x80000000u) ? ~u : (u | 0x80000000u);
}
__device__ __forceinline__ unsigned long long umin64(unsigned long long a, unsigned long long b) {
    return a < b ? a : b;
}

__device__ __forceinline__ void finish_point(
    int b, int n, float px, float py, float pz, float best, int bi,
    const float* __restrict__ P,
    int* __restrict__ p2n, float* __restrict__ dsq,
    float* __restrict__ ptx, float* __restrict__ pty, float* __restrict__ ptz,
    int* __restrict__ cnt, int* __restrict__ lst)
{
    float tx = P[0]*px + P[1]*py + P[2] *pz + P[3];
    float ty = P[4]*px + P[5]*py + P[6] *pz + P[7];
    float tz = P[8]*px + P[9]*py + P[10]*pz + P[11];
    int g = b * NN + n;
    p2n[g] = bi; dsq[g] = best;
    ptx[g] = tx; pty[g] = ty; ptz[g] = tz;
    int node = b * MM + bi;
    int s = atomicAdd(&cnt[node], 1);
    if (s < CAP) lst[node * CAP + s] = n;
}

// one thread per 2 points: argmin over 1024 keypoints (LDS-staged), transform,
// record membership. kp packed {x,y,z,|k|^2} into LDS at stage time (k_prep folded in).
__global__ __launch_bounds__(AB) void k_assign(
    const float* __restrict__ pts, const float* __restrict__ kp,
    const float* __restrict__ pose,
    int* __restrict__ p2n, float* __restrict__ dsq,
    float* __restrict__ ptx, float* __restrict__ pty, float* __restrict__ ptz,
    int* __restrict__ cnt, int* __restrict__ lst)
{
    __shared__ float4 skp[MM];                 // 16 KB
    const int b = blockIdx.y;
    for (int j = threadIdx.x; j < MM; j += AB) {
        float x = kp[(b * MM + j) * 3 + 0];
        float y = kp[(b * MM + j) * 3 + 1];
        float z = kp[(b * MM + j) * 3 + 2];
        skp[j] = make_float4(x, y, z, x * x + y * y + z * z);
    }
    __syncthreads();

    const int n0 = blockIdx.x * (AB * PPT) + threadIdx.x;
    const int n1 = n0 + AB;
    const bool v0 = n0 < NN, v1 = n1 < NN;
    const float* pb = pts + (size_t)b * NN * 3;
    float px0 = 0.f, py0 = 0.f, pz0 = 0.f;
    float px1 = 0.f, py1 = 0.f, pz1 = 0.f;
    if (v0) { px0 = pb[n0 * 3]; py0 = pb[n0 * 3 + 1]; pz0 = pb[n0 * 3 + 2]; }
    if (v1) { px1 = pb[n1 * 3]; py1 = pb[n1 * 3 + 1]; pz1 = pb[n1 * 3 + 2]; }
    const float psq0 = px0 * px0 + py0 * py0 + pz0 * pz0;
    const float psq1 = px1 * px1 + py1 * py1 + pz1 * pz1;

    float best0 = FLT_MAX, best1 = FLT_MAX;
    int bi0 = 0, bi1 = 0;
    #pragma unroll 4
    for (int j = 0; j < MM; ++j) {
        float4 q = skp[j];                     // broadcast ds_read_b128, reused 2x
        float dot0 = q.x * px0 + q.y * py0 + q.z * pz0;
        float d0 = (q.w + psq0) - 2.0f * dot0; // reference's formula
        if (d0 < best0) { best0 = d0; bi0 = j; }  // strict <: first-min (jnp.argmin)
        float dot1 = q.x * px1 + q.y * py1 + q.z * pz1;
        float d1 = (q.w + psq1) - 2.0f * dot1;
        if (d1 < best1) { best1 = d1; bi1 = j; }
    }

    const float* P = pose + b * 16;
    if (v0) finish_point(b, n0, px0, py0, pz0, best0, bi0, P, p2n, dsq, ptx, pty, ptz, cnt, lst);
    if (v1) finish_point(b, n1, px1, py1, pz1, best1, bi1, P, p2n, dsq, ptx, pty, ptz, cnt, lst);
}

// one WAVE per node (grid-stride). No same-address atomics: per-block partials.
__global__ __launch_bounds__(256) void k_node(
    const int* __restrict__ p2n, const float* __restrict__ dsq,
    const float* __restrict__ ptx, const float* __restrict__ pty, const float* __restrict__ ptz,
    const int* __restrict__ cnt, const int* __restrict__ lst,
    const float* __restrict__ kpw, const float* __restrict__ ow,
    float2* __restrict__ part)
{
    const int lane = threadIdx.x & 63;
    const int wid  = threadIdx.x >> 6;
    const int gw   = blockIdx.x * 4 + wid;        // 0..511
    const int NW   = NODEBLK * 4;
    float vacc = 0.f, wacc = 0.f;

    for (int node = gw; node < BB * MM; node += NW) {
        const int b = node >> 10;
        const int m = node & (MM - 1);
        const int base = b * NN;
        const int c = cnt[node];
        float sx = 0.f, sy = 0.f, sz = 0.f;

        if (c <= KSEL) {
            // members (one per lane) + (50-c) lowest-index non-members,
            // which provably all lie in n in [0,50).
            if (lane < c) {
                int n = lst[node * CAP + lane];
                sx = ptx[base + n]; sy = pty[base + n]; sz = ptz[base + n];
            }
            int k = KSEL - c;
            bool flag = (lane < KSEL) && (p2n[base + lane] != m);
            unsigned long long mask = __ballot(flag);
            int rank = __popcll(mask & ((1ULL << lane) - 1ULL));
            if (flag && rank < k) {
                sx += ptx[base + lane]; sy += pty[base + lane]; sz += ptz[base + lane];
            }
        } else if (c <= CAP) {
            // wave-parallel exact 50-smallest by (dist, idx); <=4 keys/lane
            unsigned long long k0 = ~0ULL, k1 = ~0ULL, k2 = ~0ULL, k3 = ~0ULL;
            {
                int s;
                s = lane;        if (s < c) { int n = lst[node*CAP+s]; k0 = ((unsigned long long)fkey(dsq[base+n])<<32)|(unsigned int)n; }
                s = lane + 64;   if (s < c) { int n = lst[node*CAP+s]; k1 = ((unsigned long long)fkey(dsq[base+n])<<32)|(unsigned int)n; }
                s = lane + 128;  if (s < c) { int n = lst[node*CAP+s]; k2 = ((unsigned long long)fkey(dsq[base+n])<<32)|(unsigned int)n; }
                s = lane + 192;  if (s < c) { int n = lst[node*CAP+s]; k3 = ((unsigned long long)fkey(dsq[base+n])<<32)|(unsigned int)n; }
            }
            unsigned long long last = 0ULL;
            int widx = -1;
            for (int r = 0; r < KSEL; ++r) {
                unsigned long long cand = k0 > last ? k0 : ~0ULL;
                cand = umin64(cand, k1 > last ? k1 : ~0ULL);
                cand = umin64(cand, k2 > last ? k2 : ~0ULL);
                cand = umin64(cand, k3 > last ? k3 : ~0ULL);
                #pragma unroll
                for (int off = 32; off; off >>= 1)
                    cand = umin64(cand, __shfl_xor(cand, off));
                last = cand;
                if (lane == r) widx = (int)(unsigned int)(cand & 0xFFFFFFFFULL);
            }
            if (widx >= 0) {   // lanes 0..49 each hold one winner: parallel loads
                sx = ptx[base + widx]; sy = pty[base + widx]; sz = ptz[base + widx];
            }
        } else {
            // pathological overflow backstop: wave-parallel rescan of all points
            unsigned long long last = 0ULL;
            int widx = -1;
            for (int r = 0; r < KSEL; ++r) {
                unsigned long long cand = ~0ULL;
                for (int n = lane; n < NN; n += 64) {
                    if (p2n[base + n] == m) {
                        unsigned long long key =
                            ((unsigned long long)fkey(dsq[base + n]) << 32) | (unsigned int)n;
                        if (key > last) cand = umin64(cand, key);
                    }
                }
                #pragma unroll
                for (int off = 32; off; off >>= 1)
                    cand = umin64(cand, __shfl_xor(cand, off));
                last = cand;
                if (lane == r) widx = (int)(unsigned int)(cand & 0xFFFFFFFFULL);
            }
            if (widx >= 0) { sx = ptx[base+widx]; sy = pty[base+widx]; sz = ptz[base+widx]; }
        }

        #pragma unroll
        for (int off = 32; off; off >>= 1) {
            sx += __shfl_xor(sx, off);
            sy += __shfl_xor(sy, off);
            sz += __shfl_xor(sz, off);
        }
        if (lane == 0) {
            const float inv = 1.0f / (float)KSEL;
            float ex = sx * inv - kpw[node * 3 + 0];
            float ey = sy * inv - kpw[node * 3 + 1];
            float ez = sz * inv - kpw[node * 3 + 2];
            float w = ow[node];
            vacc += (fabsf(ex) + fabsf(ey) + fabsf(ez)) * w;
            wacc += w;
        }
    }

    __shared__ float red[8];
    if (lane == 0) { red[wid * 2] = vacc; red[wid * 2 + 1] = wacc; }
    __syncthreads();
    if (threadIdx.x == 0)
        part[blockIdx.x] = make_float2(red[0] + red[2] + red[4] + red[6],
                                       red[1] + red[3] + red[5] + red[7]);
}

// single-wave final reduce of 128 per-block partials + divide
__global__ __launch_bounds__(64) void k_final(const float2* __restrict__ part,
                                              float* __restrict__ out) {
    int t = threadIdx.x;
    float v = part[t].x + part[t + 64].x;
    float w = part[t].y + part[t + 64].y;
    #pragma unroll
    for (int off = 32; off; off >>= 1) {
        v += __shfl_xor(v, off);
        w += __shfl_xor(w, off);
    }
    if (t == 0) out[0] = v / fmaxf(w, 1e-6f);
}

extern "C" void kernel_launch(void* const* d_in, const int* in_sizes, int n_in,
                              void* d_out, int out_size, void* d_ws, size_t ws_size,
                              hipStream_t stream) {
    const float* pts  = (const float*)d_in[0];  // B,N,3
    const float* kp   = (const float*)d_in[1];  // B,M,3
    const float* kpw  = (const float*)d_in[2];  // B,M,3
    const float* pose = (const float*)d_in[3];  // B,4,4
    const float* ow   = (const float*)d_in[4];  // B,M
    float* out = (float*)d_out;

    char* ws = (char*)d_ws;
    size_t off = 0;
    int*    cnt  = (int*)(ws + off);    off += (size_t)BB * MM * 4;        // 16 KB (zeroed)
    const size_t zero_bytes = off;
    float2* part = (float2*)(ws + off); off += (size_t)NODEBLK * 8;        // 1 KB (fully written)
    int*    p2n  = (int*)(ws + off);    off += (size_t)BB * NN * 4;
    float*  dsq  = (float*)(ws + off);  off += (size_t)BB * NN * 4;
    float*  ptx  = (float*)(ws + off);  off += (size_t)BB * NN * 4;
    float*  pty  = (float*)(ws + off);  off += (size_t)BB * NN * 4;
    float*  ptz  = (float*)(ws + off);  off += (size_t)BB * NN * 4;
    int*    lst  = (int*)(ws + off);    off += (size_t)BB * MM * CAP * 4;  // 4 MB

    hipMemsetAsync(d_ws, 0, zero_bytes, stream);

    dim3 g1((NN + AB * PPT - 1) / (AB * PPT), BB);   // (79, 4)
    k_assign<<<g1, AB, 0, stream>>>(pts, kp, pose, p2n, dsq, ptx, pty, ptz, cnt, lst);
    k_node<<<NODEBLK, 256, 0, stream>>>(p2n, dsq, ptx, pty, ptz, cnt, lst, kpw, ow, part);
    k_final<<<1, 64, 0, stream>>>(part, out);
}

// Round 4
// 128.644 us; speedup vs baseline: 5.4757x; 1.3278x over previous
//
#include <hip/hip_runtime.h>
#include <float.h>
#include <stdint.h>

#define BB 4
#define NN 20000
#define MM 1024
#define CAP 256
#define KSEL 50
#define ABLK 512            // k_assign threads = 8 waves
#define PTS_PER_BLK 128     // points per k_assign block (2 per lane)
#define KW 128              // keypoints per wave (8 waves x 128 = 1024)
#define NODEBLK 128         // k_node blocks

// order-preserving float -> uint32 map (total order incl. negatives)
__device__ __forceinline__ unsigned int fkey(float d) {
    unsigned int u = __float_as_uint(d);
    return (u & 0x80000000u) ? ~u : (u | 0x80000000u);
}
__device__ __forceinline__ float fkey_inv(unsigned int h) {
    return (h & 0x80000000u) ? __uint_as_float(h ^ 0x80000000u)
                             : __uint_as_float(~h);
}
__device__ __forceinline__ unsigned long long umin64(unsigned long long a, unsigned long long b) {
    return a < b ? a : b;
}

// 8 waves/block: same 128 points per wave, different 128-keypoint chunk each.
// In-block merge via packed keys == exact global first-min argmin.
// cnt starts at harness poison: slot = atomicAdd(cnt) - *sent.
__global__ __launch_bounds__(ABLK) void k_assign(
    const float* __restrict__ pts, const float* __restrict__ kp,
    const float* __restrict__ pose, const unsigned int* __restrict__ sent,
    int* __restrict__ p2n, float* __restrict__ dsq,
    float* __restrict__ ptx, float* __restrict__ pty, float* __restrict__ ptz,
    unsigned int* __restrict__ cnt, int* __restrict__ lst)
{
    __shared__ float4 skp[MM];                               // 16 KB
    __shared__ unsigned long long skey[8][PTS_PER_BLK];      // 8 KB
    const int b   = blockIdx.y;
    const int tid = threadIdx.x;

    for (int j = tid; j < MM; j += ABLK) {
        const float* kk = kp + ((size_t)b * MM + j) * 3;
        float x = kk[0], y = kk[1], z = kk[2];
        skp[j] = make_float4(x, y, z, x * x + y * y + z * z);
    }
    __syncthreads();

    const int w = tid >> 6, lane = tid & 63;
    const int pbase = blockIdx.x * PTS_PER_BLK;
    const int n0 = pbase + lane, n1 = n0 + 64;
    const bool v0 = n0 < NN, v1 = n1 < NN;
    const float* pb = pts + (size_t)b * NN * 3;
    float px0 = 0.f, py0 = 0.f, pz0 = 0.f, px1 = 0.f, py1 = 0.f, pz1 = 0.f;
    if (v0) { px0 = pb[n0 * 3]; py0 = pb[n0 * 3 + 1]; pz0 = pb[n0 * 3 + 2]; }
    if (v1) { px1 = pb[n1 * 3]; py1 = pb[n1 * 3 + 1]; pz1 = pb[n1 * 3 + 2]; }
    const float psq0 = px0 * px0 + py0 * py0 + pz0 * pz0;
    const float psq1 = px1 * px1 + py1 * py1 + pz1 * pz1;

    float best0 = FLT_MAX, best1 = FLT_MAX;
    int bi0 = 0, bi1 = 0;
    const int j0 = w * KW;
    #pragma unroll 8
    for (int j = 0; j < KW; ++j) {
        float4 q = skp[j0 + j];                 // broadcast ds_read_b128
        float d0 = (q.w + psq0) - 2.0f * (q.x * px0 + q.y * py0 + q.z * pz0);
        if (d0 < best0) { best0 = d0; bi0 = j0 + j; }   // reference formula + first-min
        float d1 = (q.w + psq1) - 2.0f * (q.x * px1 + q.y * py1 + q.z * pz1);
        if (d1 < best1) { best1 = d1; bi1 = j0 + j; }
    }
    skey[w][lane]      = v0 ? (((unsigned long long)fkey(best0) << 32) | (unsigned int)bi0) : ~0ULL;
    skey[w][lane + 64] = v1 ? (((unsigned long long)fkey(best1) << 32) | (unsigned int)bi1) : ~0ULL;
    __syncthreads();

    // threads 0..127 finish point pbase+tid (its coords live in this thread's regs:
    // wave0 lane t holds point t as p0; wave1 lane t-64 holds point t as p1)
    if (tid < PTS_PER_BLK) {
        const int n = pbase + tid;
        if (n < NN) {
            unsigned long long kmin = skey[0][tid];
            #pragma unroll
            for (int ww = 1; ww < 8; ++ww) kmin = umin64(kmin, skey[ww][tid]);
            const int bi = (int)(unsigned int)(kmin & 0xFFFFFFFFULL);
            const float best = fkey_inv((unsigned int)(kmin >> 32));
            const float X = (w == 0) ? px0 : px1;
            const float Y = (w == 0) ? py0 : py1;
            const float Z = (w == 0) ? pz0 : pz1;
            const float* P = pose + b * 16;
            float tx = P[0]*X + P[1]*Y + P[2] *Z + P[3];
            float ty = P[4]*X + P[5]*Y + P[6] *Z + P[7];
            float tz = P[8]*X + P[9]*Y + P[10]*Z + P[11];
            const int g = b * NN + n;
            p2n[g] = bi; dsq[g] = best;
            ptx[g] = tx; pty[g] = ty; ptz[g] = tz;
            const int node = b * MM + bi;
            unsigned int old = atomicAdd(&cnt[node], 1u);
            int s = (int)(old - *sent);
            if (s >= 0 && s < CAP) lst[node * CAP + s] = n;
        }
    }
}

// one WAVE per node (grid-stride); per-block partials + ticket: last block
// reduces and writes the final scalar (no separate k_final node).
__global__ __launch_bounds__(256) void k_node(
    const int* __restrict__ p2n, const float* __restrict__ dsq,
    const float* __restrict__ ptx, const float* __restrict__ pty, const float* __restrict__ ptz,
    const unsigned int* __restrict__ cnt, const int* __restrict__ lst,
    const float* __restrict__ kpw, const float* __restrict__ ow,
    const unsigned int* __restrict__ sent,
    float* __restrict__ part, unsigned int* __restrict__ done,
    float* __restrict__ out)
{
    const unsigned int s0 = *sent;
    const int lane = threadIdx.x & 63;
    const int wid  = threadIdx.x >> 6;
    const int gw   = blockIdx.x * 4 + wid;
    const int NW   = NODEBLK * 4;
    float vacc = 0.f, wacc = 0.f;

    for (int node = gw; node < BB * MM; node += NW) {
        const int b = node >> 10;
        const int m = node & (MM - 1);
        const int base = b * NN;
        const int c = (int)(cnt[node] - s0);
        float sx = 0.f, sy = 0.f, sz = 0.f;

        if (c <= KSEL) {
            // members + (50-c) lowest-index non-members (all in n<50)
            if (lane < c) {
                int n = lst[node * CAP + lane];
                sx = ptx[base + n]; sy = pty[base + n]; sz = ptz[base + n];
            }
            int k = KSEL - c;
            bool flag = (lane < KSEL) && (p2n[base + lane] != m);
            unsigned long long mask = __ballot(flag);
            int rank = __popcll(mask & ((1ULL << lane) - 1ULL));
            if (flag && rank < k) {
                sx += ptx[base + lane]; sy += pty[base + lane]; sz += ptz[base + lane];
            }
        } else if (c <= CAP) {
            // wave-parallel exact 50-smallest by (dist, idx)
            unsigned long long k0 = ~0ULL, k1 = ~0ULL, k2 = ~0ULL, k3 = ~0ULL;
            int s;
            s = lane;       if (s < c) { int n = lst[node*CAP+s]; k0 = ((unsigned long long)fkey(dsq[base+n])<<32)|(unsigned int)n; }
            s = lane + 64;  if (s < c) { int n = lst[node*CAP+s]; k1 = ((unsigned long long)fkey(dsq[base+n])<<32)|(unsigned int)n; }
            s = lane + 128; if (s < c) { int n = lst[node*CAP+s]; k2 = ((unsigned long long)fkey(dsq[base+n])<<32)|(unsigned int)n; }
            s = lane + 192; if (s < c) { int n = lst[node*CAP+s]; k3 = ((unsigned long long)fkey(dsq[base+n])<<32)|(unsigned int)n; }
            unsigned long long last = 0ULL;
            int widx = -1;
            for (int r = 0; r < KSEL; ++r) {
                unsigned long long cand = k0 > last ? k0 : ~0ULL;
                cand = umin64(cand, k1 > last ? k1 : ~0ULL);
                cand = umin64(cand, k2 > last ? k2 : ~0ULL);
                cand = umin64(cand, k3 > last ? k3 : ~0ULL);
                #pragma unroll
                for (int off = 32; off; off >>= 1)
                    cand = umin64(cand, __shfl_xor(cand, off));
                last = cand;
                if (lane == r) widx = (int)(unsigned int)(cand & 0xFFFFFFFFULL);
            }
            if (widx >= 0) { sx = ptx[base+widx]; sy = pty[base+widx]; sz = ptz[base+widx]; }
        } else {
            // pathological overflow backstop: rescan all points
            unsigned long long last = 0ULL;
            int widx = -1;
            for (int r = 0; r < KSEL; ++r) {
                unsigned long long cand = ~0ULL;
                for (int n = lane; n < NN; n += 64) {
                    if (p2n[base + n] == m) {
                        unsigned long long key =
                            ((unsigned long long)fkey(dsq[base + n]) << 32) | (unsigned int)n;
                        if (key > last) cand = umin64(cand, key);
                    }
                }
                #pragma unroll
                for (int off = 32; off; off >>= 1)
                    cand = umin64(cand, __shfl_xor(cand, off));
                last = cand;
                if (lane == r) widx = (int)(unsigned int)(cand & 0xFFFFFFFFULL);
            }
            if (widx >= 0) { sx = ptx[base+widx]; sy = pty[base+widx]; sz = ptz[base+widx]; }
        }

        #pragma unroll
        for (int off = 32; off; off >>= 1) {
            sx += __shfl_xor(sx, off);
            sy += __shfl_xor(sy, off);
            sz += __shfl_xor(sz, off);
        }
        if (lane == 0) {
            const float inv = 1.0f / (float)KSEL;
            float ex = sx * inv - kpw[node * 3 + 0];
            float ey = sy * inv - kpw[node * 3 + 1];
            float ez = sz * inv - kpw[node * 3 + 2];
            float w = ow[node];
            vacc += (fabsf(ex) + fabsf(ey) + fabsf(ez)) * w;
            wacc += w;
        }
    }

    __shared__ float red[8];
    __shared__ int lastflag;
    if (lane == 0) { red[wid * 2] = vacc; red[wid * 2 + 1] = wacc; }
    __syncthreads();
    if (threadIdx.x == 0) {
        // device-scope atomics: coherent across XCDs
        atomicExch(&part[2 * blockIdx.x],     red[0] + red[2] + red[4] + red[6]);
        atomicExch(&part[2 * blockIdx.x + 1], red[1] + red[3] + red[5] + red[7]);
        __threadfence();
        unsigned int t = atomicAdd(done, 1u);
        lastflag = ((int)(t - s0) == NODEBLK - 1);
    }
    __syncthreads();
    if (lastflag && threadIdx.x < 64) {
        __threadfence();
        int t = threadIdx.x;
        float v = atomicAdd(&part[2 * t], 0.f)     + atomicAdd(&part[2 * (t + 64)], 0.f);
        float w = atomicAdd(&part[2 * t + 1], 0.f) + atomicAdd(&part[2 * (t + 64) + 1], 0.f);
        #pragma unroll
        for (int off = 32; off; off >>= 1) {
            v += __shfl_xor(v, off);
            w += __shfl_xor(w, off);
        }
        if (t == 0) out[0] = v / fmaxf(w, 1e-6f);
    }
}

extern "C" void kernel_launch(void* const* d_in, const int* in_sizes, int n_in,
                              void* d_out, int out_size, void* d_ws, size_t ws_size,
                              hipStream_t stream) {
    const float* pts  = (const float*)d_in[0];  // B,N,3
    const float* kp   = (const float*)d_in[1];  // B,M,3
    const float* kpw  = (const float*)d_in[2];  // B,M,3
    const float* pose = (const float*)d_in[3];  // B,4,4
    const float* ow   = (const float*)d_in[4];  // B,M
    float* out = (float*)d_out;

    char* ws = (char*)d_ws;
    size_t off = 0;
    unsigned int* done = (unsigned int*)(ws + off); off += 4;
    unsigned int* sent = (unsigned int*)(ws + off); off += 12;   // untouched poison word
    float* part = (float*)(ws + off);  off += (size_t)NODEBLK * 2 * 4;   // 1 KB
    unsigned int* cnt = (unsigned int*)(ws + off); off += (size_t)BB * MM * 4;
    int*   p2n = (int*)(ws + off);   off += (size_t)BB * NN * 4;
    float* dsq = (float*)(ws + off); off += (size_t)BB * NN * 4;
    float* ptx = (float*)(ws + off); off += (size_t)BB * NN * 4;
    float* pty = (float*)(ws + off); off += (size_t)BB * NN * 4;
    float* ptz = (float*)(ws + off); off += (size_t)BB * NN * 4;
    int*   lst = (int*)(ws + off);   off += (size_t)BB * MM * CAP * 4;   // 4 MB

    dim3 g1((NN + PTS_PER_BLK - 1) / PTS_PER_BLK, BB);   // (157, 4)
    k_assign<<<g1, ABLK, 0, stream>>>(pts, kp, pose, sent,
                                      p2n, dsq, ptx, pty, ptz, cnt, lst);
    k_node<<<NODEBLK, 256, 0, stream>>>(p2n, dsq, ptx, pty, ptz, cnt, lst,
                                        kpw, ow, sent, part, done, out);
}

// Round 5
// 108.534 us; speedup vs baseline: 6.4903x; 1.1853x over previous
//
#include <hip/hip_runtime.h>
#include <float.h>
#include <stdint.h>

#define BB 4
#define NN 20000
#define MM 1024
#define CAP 256
#define KSEL 50
#define ABLK 512            // k_assign threads = 8 waves
#define PTS_PER_BLK 128     // points per k_assign block (2 per lane)
#define KW 128              // keypoints per wave (8 waves x 128 = 1024)
#define NODEBLK 1024        // k_node blocks: 4 waves each -> 1 node per wave

// order-preserving float -> uint32 map (total order incl. negatives)
__device__ __forceinline__ unsigned int fkey(float d) {
    unsigned int u = __float_as_uint(d);
    return (u & 0x80000000u) ? ~u : (u | 0x80000000u);
}
__device__ __forceinline__ float fkey_inv(unsigned int h) {
    return (h & 0x80000000u) ? __uint_as_float(h ^ 0x80000000u)
                             : __uint_as_float(~h);
}
__device__ __forceinline__ unsigned long long umin64(unsigned long long a, unsigned long long b) {
    return a < b ? a : b;
}

// 8 waves/block: same 128 points per wave, different 128-keypoint chunk each.
// In-block merge via packed keys == exact global first-min argmin.
// cnt starts at harness poison: slot = atomicAdd(cnt) - *sent.
__global__ __launch_bounds__(ABLK) void k_assign(
    const float* __restrict__ pts, const float* __restrict__ kp,
    const float* __restrict__ pose, const unsigned int* __restrict__ sent,
    int* __restrict__ p2n, float4* __restrict__ pt4,
    unsigned int* __restrict__ cnt, int* __restrict__ lst)
{
    __shared__ float4 skp[MM];                               // 16 KB
    __shared__ unsigned long long skey[8][PTS_PER_BLK];      // 8 KB
    const int b   = blockIdx.y;
    const int tid = threadIdx.x;

    for (int j = tid; j < MM; j += ABLK) {
        const float* kk = kp + ((size_t)b * MM + j) * 3;
        float x = kk[0], y = kk[1], z = kk[2];
        skp[j] = make_float4(x, y, z, x * x + y * y + z * z);
    }
    __syncthreads();

    const int w = tid >> 6, lane = tid & 63;
    const int pbase = blockIdx.x * PTS_PER_BLK;
    const int n0 = pbase + lane, n1 = n0 + 64;
    const bool v0 = n0 < NN, v1 = n1 < NN;
    const float* pb = pts + (size_t)b * NN * 3;
    float px0 = 0.f, py0 = 0.f, pz0 = 0.f, px1 = 0.f, py1 = 0.f, pz1 = 0.f;
    if (v0) { px0 = pb[n0 * 3]; py0 = pb[n0 * 3 + 1]; pz0 = pb[n0 * 3 + 2]; }
    if (v1) { px1 = pb[n1 * 3]; py1 = pb[n1 * 3 + 1]; pz1 = pb[n1 * 3 + 2]; }
    const float psq0 = px0 * px0 + py0 * py0 + pz0 * pz0;
    const float psq1 = px1 * px1 + py1 * py1 + pz1 * pz1;

    float best0 = FLT_MAX, best1 = FLT_MAX;
    int bi0 = 0, bi1 = 0;
    const int j0 = w * KW;
    #pragma unroll 8
    for (int j = 0; j < KW; ++j) {
        float4 q = skp[j0 + j];                 // broadcast ds_read_b128
        float d0 = (q.w + psq0) - 2.0f * (q.x * px0 + q.y * py0 + q.z * pz0);
        if (d0 < best0) { best0 = d0; bi0 = j0 + j; }   // reference formula + first-min
        float d1 = (q.w + psq1) - 2.0f * (q.x * px1 + q.y * py1 + q.z * pz1);
        if (d1 < best1) { best1 = d1; bi1 = j0 + j; }
    }
    skey[w][lane]      = v0 ? (((unsigned long long)fkey(best0) << 32) | (unsigned int)bi0) : ~0ULL;
    skey[w][lane + 64] = v1 ? (((unsigned long long)fkey(best1) << 32) | (unsigned int)bi1) : ~0ULL;
    __syncthreads();

    // threads 0..127 finish point pbase+tid (its coords live in this thread's regs:
    // wave0 lane t holds point t as p0; wave1 lane t-64 holds point t as p1)
    if (tid < PTS_PER_BLK) {
        const int n = pbase + tid;
        if (n < NN) {
            unsigned long long kmin = skey[0][tid];
            #pragma unroll
            for (int ww = 1; ww < 8; ++ww) kmin = umin64(kmin, skey[ww][tid]);
            const int bi = (int)(unsigned int)(kmin & 0xFFFFFFFFULL);
            const float best = fkey_inv((unsigned int)(kmin >> 32));
            const float X = (w == 0) ? px0 : px1;
            const float Y = (w == 0) ? py0 : py1;
            const float Z = (w == 0) ? pz0 : pz1;
            const float* P = pose + b * 16;
            float tx = P[0]*X + P[1]*Y + P[2] *Z + P[3];
            float ty = P[4]*X + P[5]*Y + P[6] *Z + P[7];
            float tz = P[8]*X + P[9]*Y + P[10]*Z + P[11];
            const int g = b * NN + n;
            p2n[g] = bi;
            pt4[g] = make_float4(tx, ty, tz, best);   // one dwordx4 store
            const int node = b * MM + bi;
            unsigned int old = atomicAdd(&cnt[node], 1u);
            int s = (int)(old - *sent);
            if (s >= 0 && s < CAP) lst[node * CAP + s] = n;
        }
    }
}

// one WAVE per node (4096 waves). Slow path = exact rank selection (no serial
// extraction). Per-block partials + ticket: last block reduces + writes out.
__global__ __launch_bounds__(256) void k_node(
    const int* __restrict__ p2n, const float4* __restrict__ pt4,
    const unsigned int* __restrict__ cnt, const int* __restrict__ lst,
    const float* __restrict__ kpw, const float* __restrict__ ow,
    const unsigned int* __restrict__ sent,
    float* __restrict__ part, unsigned int* __restrict__ done,
    float* __restrict__ out)
{
    __shared__ unsigned long long skeys[4][CAP];   // 8 KB, per-wave segments
    __shared__ float red[8];
    __shared__ int lastflag;

    const unsigned int s0 = *sent;
    const int lane = threadIdx.x & 63;
    const int wid  = threadIdx.x >> 6;
    const int node = blockIdx.x * 4 + wid;         // exactly one node per wave
    const int b = node >> 10;
    const int m = node & (MM - 1);
    const int base = b * NN;
    const int c = (int)(cnt[node] - s0);
    float sx = 0.f, sy = 0.f, sz = 0.f;

    if (c <= KSEL) {
        // members (one per lane) + (50-c) lowest-index non-members (all n<50)
        if (lane < c) {
            int n = lst[node * CAP + lane];
            float4 p = pt4[base + n];
            sx = p.x; sy = p.y; sz = p.z;
        }
        int k = KSEL - c;
        bool flag = (lane < KSEL) && (p2n[base + lane] != m);
        unsigned long long mask = __ballot(flag);
        int rank = __popcll(mask & ((1ULL << lane) - 1ULL));
        if (flag && rank < k) {
            float4 p = pt4[base + lane];
            sx += p.x; sy += p.y; sz += p.z;
        }
    } else if (c <= CAP) {
        // exact 50-smallest by (dist, idx) via parallel rank selection:
        // keys unique (idx in low bits) -> exactly 50 keys have rank < 50.
        unsigned long long kv0 = ~0ULL, kv1 = ~0ULL, kv2 = ~0ULL, kv3 = ~0ULL;
        float4 pv0 = {0,0,0,0}, pv1 = {0,0,0,0}, pv2 = {0,0,0,0}, pv3 = {0,0,0,0};
        int s;
        s = lane;       if (s < c) { int n = lst[node*CAP+s]; pv0 = pt4[base+n]; kv0 = ((unsigned long long)fkey(pv0.w)<<32)|(unsigned int)n; skeys[wid][s] = kv0; }
        s = lane + 64;  if (s < c) { int n = lst[node*CAP+s]; pv1 = pt4[base+n]; kv1 = ((unsigned long long)fkey(pv1.w)<<32)|(unsigned int)n; skeys[wid][s] = kv1; }
        s = lane + 128; if (s < c) { int n = lst[node*CAP+s]; pv2 = pt4[base+n]; kv2 = ((unsigned long long)fkey(pv2.w)<<32)|(unsigned int)n; skeys[wid][s] = kv2; }
        s = lane + 192; if (s < c) { int n = lst[node*CAP+s]; pv3 = pt4[base+n]; kv3 = ((unsigned long long)fkey(pv3.w)<<32)|(unsigned int)n; skeys[wid][s] = kv3; }
        // same-wave LDS write->read: drain lgkm, block compiler reordering
        __asm__ volatile("s_waitcnt lgkmcnt(0)" ::: "memory");
        int r0 = 0, r1 = 0, r2 = 0, r3 = 0;
        for (int j = 0; j < c; ++j) {
            unsigned long long kj = skeys[wid][j];   // broadcast read
            r0 += (kj < kv0); r1 += (kj < kv1); r2 += (kj < kv2); r3 += (kj < kv3);
        }
        // invalid keys (~0ULL) have rank >= c > 50: never selected
        if (r0 < KSEL) { sx += pv0.x; sy += pv0.y; sz += pv0.z; }
        if (r1 < KSEL) { sx += pv1.x; sy += pv1.y; sz += pv1.z; }
        if (r2 < KSEL) { sx += pv2.x; sy += pv2.y; sz += pv2.z; }
        if (r3 < KSEL) { sx += pv3.x; sy += pv3.y; sz += pv3.z; }
    } else {
        // pathological overflow backstop: serial extraction over full rescan
        unsigned long long last = 0ULL;
        int widx = -1;
        for (int r = 0; r < KSEL; ++r) {
            unsigned long long cand = ~0ULL;
            for (int n = lane; n < NN; n += 64) {
                if (p2n[base + n] == m) {
                    unsigned long long key =
                        ((unsigned long long)fkey(pt4[base + n].w) << 32) | (unsigned int)n;
                    if (key > last) cand = umin64(cand, key);
                }
            }
            #pragma unroll
            for (int off = 32; off; off >>= 1)
                cand = umin64(cand, __shfl_xor(cand, off));
            last = cand;
            if (lane == r) widx = (int)(unsigned int)(cand & 0xFFFFFFFFULL);
        }
        if (widx >= 0) { float4 p = pt4[base+widx]; sx = p.x; sy = p.y; sz = p.z; }
    }

    #pragma unroll
    for (int off = 32; off; off >>= 1) {
        sx += __shfl_xor(sx, off);
        sy += __shfl_xor(sy, off);
        sz += __shfl_xor(sz, off);
    }
    float vacc = 0.f, wacc = 0.f;
    if (lane == 0) {
        const float inv = 1.0f / (float)KSEL;
        float ex = sx * inv - kpw[node * 3 + 0];
        float ey = sy * inv - kpw[node * 3 + 1];
        float ez = sz * inv - kpw[node * 3 + 2];
        float w = ow[node];
        vacc = (fabsf(ex) + fabsf(ey) + fabsf(ez)) * w;
        wacc = w;
        red[wid * 2] = vacc; red[wid * 2 + 1] = wacc;
    }
    __syncthreads();
    if (threadIdx.x == 0) {
        // device-scope atomics: coherent across XCDs
        atomicExch(&part[2 * blockIdx.x],     red[0] + red[2] + red[4] + red[6]);
        atomicExch(&part[2 * blockIdx.x + 1], red[1] + red[3] + red[5] + red[7]);
        __threadfence();
        unsigned int t = atomicAdd(done, 1u);
        lastflag = ((int)(t - s0) == NODEBLK - 1);
    }
    __syncthreads();                 // lastflag is block-uniform after this
    if (lastflag) {
        __threadfence();
        float v = 0.f, w = 0.f;
        for (int i = threadIdx.x; i < NODEBLK; i += 256) {
            v += atomicAdd(&part[2 * i], 0.f);
            w += atomicAdd(&part[2 * i + 1], 0.f);
        }
        #pragma unroll
        for (int off = 32; off; off >>= 1) {
            v += __shfl_xor(v, off);
            w += __shfl_xor(w, off);
        }
        if (lane == 0) { red[wid * 2] = v; red[wid * 2 + 1] = w; }
        __syncthreads();
        if (threadIdx.x == 0)
            out[0] = (red[0] + red[2] + red[4] + red[6]) /
                     fmaxf(red[1] + red[3] + red[5] + red[7], 1e-6f);
    }
}

extern "C" void kernel_launch(void* const* d_in, const int* in_sizes, int n_in,
                              void* d_out, int out_size, void* d_ws, size_t ws_size,
                              hipStream_t stream) {
    const float* pts  = (const float*)d_in[0];  // B,N,3
    const float* kp   = (const float*)d_in[1];  // B,M,3
    const float* kpw  = (const float*)d_in[2];  // B,M,3
    const float* pose = (const float*)d_in[3];  // B,4,4
    const float* ow   = (const float*)d_in[4];  // B,M
    float* out = (float*)d_out;

    char* ws = (char*)d_ws;
    size_t off = 0;
    unsigned int* done = (unsigned int*)(ws + off); off += 4;
    unsigned int* sent = (unsigned int*)(ws + off); off += 12;   // untouched poison word
    float* part = (float*)(ws + off);  off += (size_t)NODEBLK * 2 * 4;     // 8 KB
    unsigned int* cnt = (unsigned int*)(ws + off); off += (size_t)BB * MM * 4;
    int*    p2n = (int*)(ws + off);    off += (size_t)BB * NN * 4;
    float4* pt4 = (float4*)(ws + off); off += (size_t)BB * NN * 16;        // 1.28 MB
    int*    lst = (int*)(ws + off);    off += (size_t)BB * MM * CAP * 4;   // 4 MB

    dim3 g1((NN + PTS_PER_BLK - 1) / PTS_PER_BLK, BB);   // (157, 4)
    k_assign<<<g1, ABLK, 0, stream>>>(pts, kp, pose, sent, p2n, pt4, cnt, lst);
    k_node<<<NODEBLK, 256, 0, stream>>>(p2n, pt4, cnt, lst, kpw, ow, sent,
                                        part, done, out);
}